// Round 3
// baseline (180.677 us; speedup 1.0000x reference)
//
#include <hip/hip_runtime.h>

#pragma clang fp contract(off)

#define B 16
#define A 3
#define HGT 52
#define WID 52
#define HW 2704
#define NCAND 8112   // A*HW
#define CATTR 25
#define TOPK 2048
#define NWORD 64     // 64 u32 words x 32 bits = 2048 cols
#define CH 256       // rows per scan chunk
#define NCHUNK (TOPK / CH)   // 8
#define GPC (CH / 32)        // 8 groups per chunk
#define CHP 260      // padded chunk-row stride (words); %4==0 keeps b128 align
#define EPT 8        // sort: elements per thread

typedef unsigned int uint32;
typedef unsigned long long u64;

// ---------------- decode ----------------
// Writes out[b,n,25] (via LDS transpose, coalesced) + conf for the sort +
// a packed 8-float geometry record pk[b,n,8] = {x1,y1,x2,y2, area, cls,
// valid, 0} so the post-topk gather reads 32 B instead of 100 B.
// All f32 ops in the same order as the reference -> bit-identical.
__global__ __launch_bounds__(256) void decode_kernel(const float* __restrict__ inp,
                                                     const float* __restrict__ anchors,
                                                     float* __restrict__ out,
                                                     float* __restrict__ cws,
                                                     float* __restrict__ pk) {
    __shared__ float sm[256 * CATTR];   // 25.6 KiB, candidate-major == out order
    int tid = threadIdx.x;
    int t = blockIdx.x * 256 + tid;     // < B*NCAND (129792 = 507*256 exactly)
    int b  = t / NCAND;
    int n  = t - b * NCAND;
    int a  = n / HW;
    int hw = n - a * HW;
    int gy = hw / WID;
    int gx = hw - gy * WID;
    const float* ip = inp + ((size_t)(b * (A * CATTR) + a * CATTR)) * HW + hw;
    float* sp = sm + tid * CATTR;

    float p0 = ip[0 * HW], p1 = ip[1 * HW], p2 = ip[2 * HW], p3 = ip[3 * HW], p4 = ip[4 * HW];
    float sx = 1.0f / (1.0f + expf(-p0));
    float sy = 1.0f / (1.0f + expf(-p1));
    float bx = (sx + (float)gx) * 8.0f;   // stride = 8 exactly
    float by = (sy + (float)gy) * 8.0f;
    float bw = expf(p2) * anchors[a * 2 + 0];   // (anchor/8)*8 exact
    float bh = expf(p3) * anchors[a * 2 + 1];
    float cf = 1.0f / (1.0f + expf(-p4));
    sp[0] = bx; sp[1] = by; sp[2] = bw; sp[3] = bh; sp[4] = cf;
    cws[t] = cf;   // contiguous conf for the sort

    float best = -1.0f; int bc = 0;
#pragma unroll
    for (int c = 0; c < 20; ++c) {
        float v = ip[(5 + c) * HW];
        float s = 1.0f / (1.0f + expf(-v));
        sp[5 + c] = s;
        if (s > best) { best = s; bc = c; }   // first-max (numpy semantics;
    }                                         // sigmoid>0 so c=0 always sets)

    // packed geometry record (same op order as old geo: w*0.5f exact)
    float hw_ = bw * 0.5f, hh_ = bh * 0.5f;
    float x1 = bx - hw_, y1 = by - hh_, x2 = bx + hw_, y2 = by + hh_;
    float area = ((x2 - x1) + 1.0f) * ((y2 - y1) + 1.0f);
    float4* pk4 = (float4*)(pk + (size_t)t * 8);
    pk4[0] = make_float4(x1, y1, x2, y2);
    pk4[1] = make_float4(area, (float)bc, (cf >= 0.5f) ? 1.0f : 0.0f, 0.0f);

    __syncthreads();
    const float4* sm4 = (const float4*)sm;
    float4* o4 = (float4*)(out + (size_t)blockIdx.x * 256 * CATTR);
#pragma unroll
    for (int k = 0; k < 6; ++k) o4[k * 256 + tid] = sm4[k * 256 + tid];
    if (tid < 64) o4[1536 + tid] = sm4[1536 + tid];
}

// ---------------- sort helpers ----------------
// key = (~(conf_bits|sign) << 32) | idx ; ascending == conf desc, idx asc.
// Keys are UNIQUE (idx in low bits) -> strict total order (pads ~0ull sort
// last and can never reach the top-2048: 8112 real keys > 2048).
__device__ __forceinline__ void cexd(u64& a, u64& b, bool up) {
    if ((a > b) == up) { u64 tmp = a; a = b; b = tmp; }
}

__device__ __forceinline__ u64 sel(u64 k, u64 o, bool kmin) {
    return kmin ? (k < o ? k : o) : (k > o ? k : o);
}

// merge-path rank: rank r of merge(A,B), both len 2048, r < 2048 -> i in [0, r].
__device__ __forceinline__ u64 merge_rank(const u64* __restrict__ Aa,
                                          const u64* __restrict__ Bb, int r) {
    int lo = 0, hi = r;
    while (lo < hi) {
        int mid = (lo + hi) >> 1;
        if (Aa[mid] < Bb[r - 1 - mid]) lo = mid + 1; else hi = mid;
    }
    u64 av = Aa[lo], bv = Bb[r - lo];
    return av < bv ? av : bv;
}

// ---------------- sortsel: fused chunk-sort + merge tree + gather ----------
// One block per batch, 1024 threads. The four 2048-key bitonic chunk-sorts
// run as four concurrent 256-thread groups (per-chunk LDS mailbox slices;
// all groups execute identical data-independent barrier sequences, so
// block-wide __syncthreads is safe). Sorted runs land in LDS; merge-path
// tree + pk gather + vwords ballot follow in the same kernel. Kills the
// runs HBM round-trip, one launch, and the global re-stage.
__global__ __launch_bounds__(1024) void sortsel_kernel(const float* __restrict__ conf,
                                                       const float* __restrict__ pk,
                                                       float* __restrict__ topf,
                                                       float* __restrict__ gx1,
                                                       float* __restrict__ gy1,
                                                       float* __restrict__ gx2,
                                                       float* __restrict__ gy2,
                                                       float* __restrict__ gar,
                                                       uint32* __restrict__ gcv,
                                                       uint32* __restrict__ vwords) {
    __shared__ u64 smem[12288];   // 96 KiB: [0,8192) mailbox->sorted runs; [8192,12288) merged
    int bt  = blockIdx.x;
    int tid = threadIdx.x;
    int g   = tid >> 8;            // chunk 0..3
    int t   = tid & 255;           // thread within chunk-sorter
    int base  = t * EPT;           // local 0..2047
    int gbase = g * 2048 + base;   // candidate index in batch
    const float* cp = conf + bt * NCAND;
    u64* mb = smem + g * 2048;     // this chunk's 16 KiB mailbox slice

    // ---- load & build keys (identical to old sort1) ----
    u64 key[EPT];
    if (gbase + EPT <= NCAND) {
        const float4* cp4 = (const float4*)(cp + gbase);
        float4 c0 = cp4[0], c1 = cp4[1];
        float cf[EPT] = {c0.x, c0.y, c0.z, c0.w, c1.x, c1.y, c1.z, c1.w};
#pragma unroll
        for (int e = 0; e < EPT; ++e) {
            unsigned bits = __float_as_uint(cf[e]) | 0x80000000u;
            key[e] = ((u64)(~bits) << 32) | (unsigned)(gbase + e);
        }
    } else {
#pragma unroll
        for (int e = 0; e < EPT; ++e) {
            int idx = gbase + e;
            if (idx < NCAND) {
                unsigned bits = __float_as_uint(cp[idx]) | 0x80000000u;
                key[e] = ((u64)(~bits) << 32) | (unsigned)idx;
            } else key[e] = ~0ull;   // pad sorts last
        }
    }

    // ---- bitonic sort of 2048 within the 256-thread group ----
    cexd(key[0], key[1], true); cexd(key[2], key[3], false);
    cexd(key[4], key[5], true); cexd(key[6], key[7], false);

    cexd(key[0], key[2], true);  cexd(key[1], key[3], true);
    cexd(key[4], key[6], false); cexd(key[5], key[7], false);
    cexd(key[0], key[1], true);  cexd(key[2], key[3], true);
    cexd(key[4], key[5], false); cexd(key[6], key[7], false);

    bool up8 = ((t & 1) == 0);
    cexd(key[0], key[4], up8); cexd(key[1], key[5], up8);
    cexd(key[2], key[6], up8); cexd(key[3], key[7], up8);
    cexd(key[0], key[2], up8); cexd(key[1], key[3], up8);
    cexd(key[4], key[6], up8); cexd(key[5], key[7], up8);
    cexd(key[0], key[1], up8); cexd(key[2], key[3], up8);
    cexd(key[4], key[5], up8); cexd(key[6], key[7], up8);

    for (unsigned k = 16; k <= 2048; k <<= 1) {
        bool up = (((unsigned)base & k) == 0);
        for (unsigned j = k >> 1; j >= 8; j >>= 1) {
            unsigned m = j >> 3;
            bool kmin = (up == ((t & (int)m) == 0));
            if (m >= 64) {
                __syncthreads();
#pragma unroll
                for (int e = 0; e < EPT; ++e) mb[e * 256 + t] = key[e];
                __syncthreads();
                int pt = t ^ (int)m;
#pragma unroll
                for (int e = 0; e < EPT; ++e) key[e] = sel(key[e], mb[e * 256 + pt], kmin);
            } else {
#pragma unroll
                for (int e = 0; e < EPT; ++e) {
                    u64 o = __shfl_xor(key[e], (int)m);   // m<64: stays in-wave
                    key[e] = sel(key[e], o, kmin);
                }
            }
        }
        cexd(key[0], key[4], up); cexd(key[1], key[5], up);
        cexd(key[2], key[6], up); cexd(key[3], key[7], up);
        cexd(key[0], key[2], up); cexd(key[1], key[3], up);
        cexd(key[4], key[6], up); cexd(key[5], key[7], up);
        cexd(key[0], key[1], up); cexd(key[2], key[3], up);
        cexd(key[4], key[5], up); cexd(key[6], key[7], up);
    }

    // ---- deposit sorted run contiguously (run g at smem[g*2048 ..)) ----
    __syncthreads();   // all mailbox reads done before layout change
#pragma unroll
    for (int e = 0; e < EPT; ++e) mb[base + e] = key[e];
    __syncthreads();

    // ---- phase 1: pair merges (run0,run1)->m[0..2047], (run2,run3)->m[2048..4095]
    u64* m = smem + 8192;
    u64 v[4];
#pragma unroll
    for (int k2 = 0; k2 < 4; ++k2) {
        int o = tid + k2 * 1024;         // output index in [0, 4096)
        int p = o >> 11, r = o & 2047;
        const u64* Aa = smem + p * 4096;
        const u64* Bb = Aa + 2048;
        v[k2] = merge_rank(Aa, Bb, r);   // reads [0,8192) only
    }
#pragma unroll
    for (int k2 = 0; k2 < 4; ++k2) m[tid + k2 * 1024] = v[k2];  // writes [8192,12288)
    __syncthreads();

    // ---- phase 2: final top-2048 + packed gather + vwords ballot ----
#pragma unroll
    for (int k2 = 0; k2 < 2; ++k2) {
        int r = tid + k2 * 1024;         // consecutive r across each wave
        u64 kk = merge_rank(m, m + 2048, r);
        unsigned idx = (unsigned)(kk & 0xFFFFFFFFu);
        int to = bt * TOPK + r;
        topf[to] = (float)idx;
        const float4* p4 = (const float4*)(pk + ((size_t)bt * NCAND + idx) * 8);
        float4 g0 = p4[0], g1 = p4[1];
        gx1[to] = g0.x; gy1[to] = g0.y; gx2[to] = g0.z; gy2[to] = g0.w;
        gar[to] = g1.x;
        gcv[to] = (uint32)g1.y;
        bool valid = (g1.z != 0.0f);
        unsigned long long bal = __ballot(valid);   // r wave-aligned (64 consecutive rows)
        if ((tid & 63) == 0) {
            vwords[(to >> 5) + 0] = (uint32)bal;
            vwords[(to >> 5) + 1] = (uint32)(bal >> 32);
        }
    }
}

// ---------------- NMS stage 2: suppression bitmask build (TRANSPOSED) -----
// rmT[word][row] per batch. Strict upper triangle; diagonal scrubbed here.
// Exact div-free IoU threshold (R5 proof).
#define KMID (13421772.5 / 33554432.0)
__global__ __launch_bounds__(1024) void build_kernel(const float* __restrict__ gx1,
                                                     const float* __restrict__ gy1,
                                                     const float* __restrict__ gx2,
                                                     const float* __restrict__ gy2,
                                                     const float* __restrict__ gar,
                                                     const uint32* __restrict__ gcv,
                                                     uint32* __restrict__ rowmask) {
    __shared__ float  x1s[TOPK], y1s[TOPK], x2s[TOPK], y2s[TOPK];  // 32 KiB
    __shared__ uint32 clss[TOPK];                                  // 8 KiB
    int bt   = blockIdx.y;
    int pr   = blockIdx.x;          // pair 0..15
    int tid  = threadIdx.x;
    int lane = tid & 63;
    int wv   = tid >> 6;            // wave 0..15
    int base = bt * TOPK;
    uint32* rmT = rowmask + (size_t)base * NWORD;   // [word][2048]

    for (int j = tid; j < TOPK; j += 1024) {
        int g = base + j;
        x1s[j] = gx1[g]; y1s[j] = gy1[g]; x2s[j] = gx2[g]; y2s[j] = gy2[g];
        clss[j] = gcv[g] & 0xffu;
    }
    __syncthreads();

    int r  = (wv >> 3) ? (31 - pr) : pr;   // strip index
    int i0 = r * 64 + (wv & 7) * 8;        // this wave's 8 rows

    float rx1[8], ry1[8], rx2[8], ry2[8], rar[8];
    uint32 rcl[8];
#pragma unroll
    for (int k = 0; k < 8; ++k) {
        rx1[k] = x1s[i0 + k]; ry1[k] = y1s[i0 + k];
        rx2[k] = x2s[i0 + k]; ry2[k] = y2s[i0 + k];
        rar[k] = ((rx2[k] - rx1[k]) + 1.0f) * ((ry2[k] - ry1[k]) + 1.0f);
        rcl[k] = clss[i0 + k];
    }

    int j0 = r * 64 + lane;
    float cx1 = x1s[j0], cy1 = y1s[j0], cx2 = x2s[j0], cy2 = y2s[j0];
    uint32 cc = clss[j0];

    for (int cg = r; cg < 32; ++cg) {
        float nx1 = 0.f, ny1 = 0.f, nx2 = 0.f, ny2 = 0.f; uint32 nc = 0;
        if (cg + 1 < 32) {      // prefetch next column group
            int nj = (cg + 1) * 64 + lane;
            nx1 = x1s[nj]; ny1 = y1s[nj]; nx2 = x2s[nj]; ny2 = y2s[nj];
            nc = clss[nj];
        }
        float car = ((cx2 - cx1) + 1.0f) * ((cy2 - cy1) + 1.0f);
        u64 bal[8];
#pragma unroll
        for (int k = 0; k < 8; ++k) {
            float ix1 = fmaxf(rx1[k], cx1);
            float iy1 = fmaxf(ry1[k], cy1);
            float ix2 = fminf(rx2[k], cx2);
            float iy2 = fminf(ry2[k], cy2);
            float iw = fmaxf((ix2 - ix1) + 1.0f, 0.0f);
            float ih = fmaxf((iy2 - iy1) + 1.0f, 0.0f);
            float inter = iw * ih;
            float denom = ((rar[k] + car) - inter) + 1e-16f;
            bool cond = ((double)inter > KMID * (double)denom) && (cc == rcl[k]);
            bal[k] = __ballot(cond);
        }
        // pack: lanes 0..7 -> low words, lanes 8..15 -> high words of rows i0..i0+7
        u64 v = bal[0];
#pragma unroll
        for (int k = 1; k < 8; ++k) if ((lane & 7) == k) v = bal[k];
        uint32 w32 = (lane & 8) ? (uint32)(v >> 32) : (uint32)v;
        int gi = i0 + (lane & 7);
        int wd = 2 * cg + ((lane >> 3) & 1);
        if (wd == (gi >> 5)) w32 &= ~((2u << (gi & 31)) - 1u);   // diagonal scrub
        if (lane < 16) rmT[(size_t)wd * TOPK + gi] = w32;
        cx1 = nx1; cy1 = ny1; cx2 = nx2; cy2 = ny2; cc = nc;
    }
}

// ---------------- NMS scan copy: global_load_lds DMA ----------------
// rmT is [word][row]. For chunk c, word w covers rows c*256..+255 -> ONE
// global_load_lds dwordx4 per word. Trim w >= 8c (dead below).
__device__ __forceinline__ void copy_chunk_dma(const uint32* __restrict__ rmT,
                                               uint32* dstL, int c, int wvm1, int lane) {
    int wmin = 8 * c;
    for (int w = wmin + wvm1; w < 64; w += 15) {
        const uint32* gp = rmT + (size_t)w * TOPK + c * CH + lane * 4;
        uint32* lp = dstL + w * CHP;
        __builtin_amdgcn_global_load_lds((const __attribute__((address_space(1))) void*)gp,
                                         (__attribute__((address_space(3))) void*)lp,
                                         16, 0, 0);
    }
}

// ---------------- NMS stage 3: group-batched greedy scan ----------------
__global__ __launch_bounds__(1024) void scan_kernel(const uint32* __restrict__ rowmask,
                                                    const uint32* __restrict__ vwords,
                                                    float* __restrict__ keepf) {
    __shared__ uint32 buf[2][64 * CHP];   // 2 x 66,560 B
    int bt  = blockIdx.x;
    int tid = threadIdx.x;
    int wv  = tid >> 6;
    int l   = tid & 63;
    const uint32* rmT = rowmask + (size_t)bt * TOPK * NWORD;

    uint32 supp = 0, keepw = 0;
    if (wv == 0) supp = ~vwords[bt * 64 + l];

    if (wv > 0) copy_chunk_dma(rmT, buf[0], 0, wv - 1, l);
    __syncthreads();

    for (int c = 0; c < NCHUNK; ++c) {
        if (wv > 0) {
            if (c + 1 < NCHUNK) copy_chunk_dma(rmT, buf[(c + 1) & 1], c + 1, wv - 1, l);
        } else {
            const uint32* bp = buf[c & 1];
            uint4 sq[8];
            {
                int g0 = c * GPC;
                const uint4* sp = (const uint4*)(bp + g0 * CHP);
#pragma unroll
                for (int q = 0; q < 8; ++q) sq[q] = sp[q];
            }
            for (int gl = 0; gl < GPC; ++gl) {
                int g = c * GPC + gl;
                uint4 rwq[8];
                const uint4* rp = (const uint4*)(bp + l * CHP + gl * 32);
#pragma unroll
                for (int q = 0; q < 8; ++q) rwq[q] = rp[q];
                uint32 cur = __builtin_amdgcn_readlane(supp, g);
#pragma unroll
                for (int q = 0; q < 8; ++q) {
                    uint32 s0 = sq[q].x, s1 = sq[q].y, s2 = sq[q].z, s3 = sq[q].w;
                    int k = q * 4;
                    cur |= s0 & ((((cur >> (k + 0)) & 1u)) - 1u);
                    cur |= s1 & ((((cur >> (k + 1)) & 1u)) - 1u);
                    cur |= s2 & ((((cur >> (k + 2)) & 1u)) - 1u);
                    cur |= s3 & ((((cur >> (k + 3)) & 1u)) - 1u);
                }
                uint32 keep = ~cur;
                if (l == g) keepw = keep;
                if (gl + 1 < GPC) {
                    const uint4* sp = (const uint4*)(bp + (g + 1) * CHP + (gl + 1) * 32);
#pragma unroll
                    for (int q = 0; q < 8; ++q) sq[q] = sp[q];
                }
                uint32 upd = 0;
#pragma unroll
                for (int q = 0; q < 8; ++q) {
                    int k = q * 4;
                    upd |= rwq[q].x & (uint32)(((int)(keep << (31 - (k + 0)))) >> 31);
                    upd |= rwq[q].y & (uint32)(((int)(keep << (31 - (k + 1)))) >> 31);
                    upd |= rwq[q].z & (uint32)(((int)(keep << (31 - (k + 2)))) >> 31);
                    upd |= rwq[q].w & (uint32)(((int)(keep << (31 - (k + 3)))) >> 31);
                }
                supp |= upd;
            }
        }
        __syncthreads();
    }

    if (wv == 0) {
#pragma unroll
        for (int k = 0; k < 32; ++k)
            keepf[bt * TOPK + l * 32 + k] = (float)((keepw >> k) & 1u);
    }
}

extern "C" void kernel_launch(void* const* d_in, const int* in_sizes, int n_in,
                              void* d_out, int out_size, void* d_ws, size_t ws_size,
                              hipStream_t stream) {
    const float* inp     = (const float*)d_in[0];
    const float* anchors = (const float*)d_in[1];
    float* out   = (float*)d_out;                        // [B, N, 25]
    float* topf  = out  + (size_t)B * NCAND * CATTR;     // [B, 2048] indices as float
    float* keepf = topf + (size_t)B * TOPK;              // [B, 2048] 0/1 as float

    // workspace layout
    float*  cws = (float*)d_ws;                          // [B, NCAND] conf
    float*  pk  = cws + B * NCAND;                       // [B, NCAND, 8] packed geom
    float*  gx1 = pk  + (size_t)B * NCAND * 8;
    float*  gy1 = gx1 + B * TOPK;
    float*  gx2 = gy1 + B * TOPK;
    float*  gy2 = gx2 + B * TOPK;
    float*  gar = gy2 + B * TOPK;
    uint32* gcv = (uint32*)(gar + B * TOPK);
    uint32* rowmask = gcv + B * TOPK;                    // rmT: [B][64][2048] u32 = 8 MiB
    uint32* vwords  = rowmask + (size_t)B * TOPK * NWORD;

    decode_kernel<<<(B * NCAND) / 256, 256, 0, stream>>>(inp, anchors, out, cws, pk);
    sortsel_kernel<<<B, 1024, 0, stream>>>(cws, pk, topf, gx1, gy1, gx2, gy2, gar, gcv, vwords);
    build_kernel<<<dim3(16, B), 1024, 0, stream>>>(gx1, gy1, gx2, gy2, gar, gcv, rowmask);
    scan_kernel<<<B, 1024, 0, stream>>>(rowmask, vwords, keepf);
}

// Round 4
// 169.214 us; speedup vs baseline: 1.0677x; 1.0677x over previous
//
#include <hip/hip_runtime.h>

#pragma clang fp contract(off)

#define B 16
#define A 3
#define HGT 52
#define WID 52
#define HW 2704
#define NCAND 8112   // A*HW
#define CATTR 25
#define TOPK 2048
#define NWORD 64     // 64 u32 words x 32 bits = 2048 cols
#define CH 256       // rows per scan chunk
#define NCHUNK (TOPK / CH)   // 8
#define GPC (CH / 32)        // 8 groups per chunk
#define CHP 260      // padded chunk-row stride (words); %4==0 keeps b128 align
#define EPT 8        // sort: elements per thread

typedef unsigned int uint32;
typedef unsigned long long u64;

// ---------------- decode ----------------
// Writes out[b,n,25] (via LDS transpose, coalesced) + conf for the sort +
// a packed 8-float geometry record pk[b,n,8] = {x1,y1,x2,y2, area, cls,
// valid, 0} so the post-topk gather reads 32 B instead of 100 B.
// All f32 ops in the same order as the reference -> bit-identical.
__global__ __launch_bounds__(256) void decode_kernel(const float* __restrict__ inp,
                                                     const float* __restrict__ anchors,
                                                     float* __restrict__ out,
                                                     float* __restrict__ cws,
                                                     float* __restrict__ pk) {
    __shared__ float sm[256 * CATTR];   // 25.6 KiB, candidate-major == out order
    int tid = threadIdx.x;
    int t = blockIdx.x * 256 + tid;     // < B*NCAND (129792 = 507*256 exactly)
    int b  = t / NCAND;
    int n  = t - b * NCAND;
    int a  = n / HW;
    int hw = n - a * HW;
    int gy = hw / WID;
    int gx = hw - gy * WID;
    const float* ip = inp + ((size_t)(b * (A * CATTR) + a * CATTR)) * HW + hw;
    float* sp = sm + tid * CATTR;

    float p0 = ip[0 * HW], p1 = ip[1 * HW], p2 = ip[2 * HW], p3 = ip[3 * HW], p4 = ip[4 * HW];
    float sx = 1.0f / (1.0f + expf(-p0));
    float sy = 1.0f / (1.0f + expf(-p1));
    float bx = (sx + (float)gx) * 8.0f;   // stride = 8 exactly
    float by = (sy + (float)gy) * 8.0f;
    float bw = expf(p2) * anchors[a * 2 + 0];   // (anchor/8)*8 exact
    float bh = expf(p3) * anchors[a * 2 + 1];
    float cf = 1.0f / (1.0f + expf(-p4));
    sp[0] = bx; sp[1] = by; sp[2] = bw; sp[3] = bh; sp[4] = cf;
    cws[t] = cf;   // contiguous conf for the sort

    float best = -1.0f; int bc = 0;
#pragma unroll
    for (int c = 0; c < 20; ++c) {
        float v = ip[(5 + c) * HW];
        float s = 1.0f / (1.0f + expf(-v));
        sp[5 + c] = s;
        if (s > best) { best = s; bc = c; }   // first-max (numpy semantics;
    }                                         // sigmoid>0 so c=0 always sets)

    // packed geometry record (same op order as old geo: w*0.5f exact)
    float hw_ = bw * 0.5f, hh_ = bh * 0.5f;
    float x1 = bx - hw_, y1 = by - hh_, x2 = bx + hw_, y2 = by + hh_;
    float area = ((x2 - x1) + 1.0f) * ((y2 - y1) + 1.0f);
    float4* pk4 = (float4*)(pk + (size_t)t * 8);
    pk4[0] = make_float4(x1, y1, x2, y2);
    pk4[1] = make_float4(area, (float)bc, (cf >= 0.5f) ? 1.0f : 0.0f, 0.0f);

    __syncthreads();
    const float4* sm4 = (const float4*)sm;
    float4* o4 = (float4*)(out + (size_t)blockIdx.x * 256 * CATTR);
#pragma unroll
    for (int k = 0; k < 6; ++k) o4[k * 256 + tid] = sm4[k * 256 + tid];
    if (tid < 64) o4[1536 + tid] = sm4[1536 + tid];
}

// ---------------- sort helpers ----------------
// key = (~(conf_bits|sign) << 32) | idx ; ascending == conf desc, idx asc.
// Keys are UNIQUE (idx in low bits) -> strict total order (pads ~0ull sort
// last and can never reach the top-2048: 8112 real keys > 2048).
__device__ __forceinline__ void cexd(u64& a, u64& b, bool up) {
    if ((a > b) == up) { u64 tmp = a; a = b; b = tmp; }
}

__device__ __forceinline__ u64 sel(u64 k, u64 o, bool kmin) {
    return kmin ? (k < o ? k : o) : (k > o ? k : o);
}

// ---------------- S1: sort each 2048-chunk ascending ----------------
__global__ __launch_bounds__(256) void sort1_kernel(const float* __restrict__ conf,
                                                    u64* __restrict__ runs) {
    __shared__ u64 mb[2048];   // 16 KiB SoA mailbox
    int blk = blockIdx.x;
    int b = blk >> 2, c = blk & 3;
    int t = threadIdx.x;
    int base = t * EPT;               // local 0..2047
    int gbase = c * 2048 + base;      // candidate index in batch
    const float* cp = conf + b * NCAND;

    u64 key[EPT];
    if (gbase + EPT <= NCAND) {
        const float4* cp4 = (const float4*)(cp + gbase);
        float4 c0 = cp4[0], c1 = cp4[1];
        float cf[EPT] = {c0.x, c0.y, c0.z, c0.w, c1.x, c1.y, c1.z, c1.w};
#pragma unroll
        for (int e = 0; e < EPT; ++e) {
            unsigned bits = __float_as_uint(cf[e]) | 0x80000000u;
            key[e] = ((u64)(~bits) << 32) | (unsigned)(gbase + e);
        }
    } else {
#pragma unroll
        for (int e = 0; e < EPT; ++e) {
            int idx = gbase + e;
            if (idx < NCAND) {
                unsigned bits = __float_as_uint(cp[idx]) | 0x80000000u;
                key[e] = ((u64)(~bits) << 32) | (unsigned)idx;
            } else key[e] = ~0ull;   // pad sorts last
        }
    }

    cexd(key[0], key[1], true); cexd(key[2], key[3], false);
    cexd(key[4], key[5], true); cexd(key[6], key[7], false);

    cexd(key[0], key[2], true);  cexd(key[1], key[3], true);
    cexd(key[4], key[6], false); cexd(key[5], key[7], false);
    cexd(key[0], key[1], true);  cexd(key[2], key[3], true);
    cexd(key[4], key[5], false); cexd(key[6], key[7], false);

    bool up8 = ((t & 1) == 0);
    cexd(key[0], key[4], up8); cexd(key[1], key[5], up8);
    cexd(key[2], key[6], up8); cexd(key[3], key[7], up8);
    cexd(key[0], key[2], up8); cexd(key[1], key[3], up8);
    cexd(key[4], key[6], up8); cexd(key[5], key[7], up8);
    cexd(key[0], key[1], up8); cexd(key[2], key[3], up8);
    cexd(key[4], key[5], up8); cexd(key[6], key[7], up8);

    for (unsigned k = 16; k <= 2048; k <<= 1) {
        bool up = (((unsigned)base & k) == 0);
        for (unsigned j = k >> 1; j >= 8; j >>= 1) {
            unsigned m = j >> 3;
            bool kmin = (up == ((t & m) == 0));
            if (m >= 64) {
                __syncthreads();
#pragma unroll
                for (int e = 0; e < EPT; ++e) mb[e * 256 + t] = key[e];
                __syncthreads();
                int pt = t ^ (int)m;
#pragma unroll
                for (int e = 0; e < EPT; ++e) key[e] = sel(key[e], mb[e * 256 + pt], kmin);
            } else {
#pragma unroll
                for (int e = 0; e < EPT; ++e) {
                    u64 o = __shfl_xor(key[e], (int)m);
                    key[e] = sel(key[e], o, kmin);
                }
            }
        }
        cexd(key[0], key[4], up); cexd(key[1], key[5], up);
        cexd(key[2], key[6], up); cexd(key[3], key[7], up);
        cexd(key[0], key[2], up); cexd(key[1], key[3], up);
        cexd(key[4], key[6], up); cexd(key[5], key[7], up);
        cexd(key[0], key[1], up); cexd(key[2], key[3], up);
        cexd(key[4], key[5], up); cexd(key[6], key[7], up);
    }

    u64* R = runs + ((size_t)b * 4 + c) * 2048;
#pragma unroll
    for (int e = 0; e < EPT; ++e) R[base + e] = key[e];
}

// ---------------- merge-path rank (shared by topsel) ----------------
// rank r of merge(A,B), both len 2048, r < 2048 -> i in [0, r].
__device__ __forceinline__ u64 merge_rank(const u64* __restrict__ Aa,
                                          const u64* __restrict__ Bb, int r) {
    int lo = 0, hi = r;
    while (lo < hi) {
        int mid = (lo + hi) >> 1;
        if (Aa[mid] < Bb[r - 1 - mid]) lo = mid + 1; else hi = mid;
    }
    u64 av = Aa[lo], bv = Bb[r - lo];
    return av < bv ? av : bv;
}

// ---------------- topsel: fused merge tree + gather (was merge1+merge2+geo)
// One block per batch (1024 threads). Stage the 4 sorted runs (64 KiB) in
// LDS, two merge-path phases entirely in LDS, then gather pk and emit
// topf / geometry SoA / vwords directly. 3 launches -> 1; binary searches
// hit LDS instead of L2/L3; mruns intermediate never touches global.
__global__ __launch_bounds__(1024) void topsel_kernel(const u64* __restrict__ runs,
                                                      const float* __restrict__ pk,
                                                      float* __restrict__ topf,
                                                      float* __restrict__ gx1,
                                                      float* __restrict__ gy1,
                                                      float* __restrict__ gx2,
                                                      float* __restrict__ gy2,
                                                      float* __restrict__ gar,
                                                      uint32* __restrict__ gcv,
                                                      uint32* __restrict__ vwords) {
    __shared__ u64 lds[12288];   // 96 KiB: [0,8192) = 4 runs, [8192,12288) = 2 merged
    int bt  = blockIdx.x;
    int tid = threadIdx.x;
    const u64* R = runs + (size_t)bt * 8192;

    // stage the 4 runs, coalesced
#pragma unroll
    for (int k = 0; k < 8; ++k) lds[tid + k * 1024] = R[tid + k * 1024];
    __syncthreads();

    // phase 1: pair merges (run0,run1)->m[0..2047], (run2,run3)->m[2048..4095]
    u64* m = lds + 8192;
    u64 v[4];
#pragma unroll
    for (int k = 0; k < 4; ++k) {
        int o = tid + k * 1024;          // output index in [0, 4096)
        int p = o >> 11, r = o & 2047;
        const u64* Aa = lds + p * 4096;
        const u64* Bb = Aa + 2048;
        v[k] = merge_rank(Aa, Bb, r);    // reads [0,8192) only
    }
#pragma unroll
    for (int k = 0; k < 4; ++k) m[tid + k * 1024] = v[k];   // writes [8192,12288) only
    __syncthreads();

    // phase 2: final top-2048 + packed gather + vwords ballot
#pragma unroll
    for (int k = 0; k < 2; ++k) {
        int r = tid + k * 1024;          // consecutive r across each wave
        u64 key = merge_rank(m, m + 2048, r);
        unsigned idx = (unsigned)(key & 0xFFFFFFFFu);
        int t = bt * TOPK + r;
        topf[t] = (float)idx;
        const float4* p4 = (const float4*)(pk + ((size_t)bt * NCAND + idx) * 8);
        float4 g0 = p4[0], g1 = p4[1];
        gx1[t] = g0.x; gy1[t] = g0.y; gx2[t] = g0.z; gy2[t] = g0.w;
        gar[t] = g1.x;
        gcv[t] = (uint32)g1.y;
        bool valid = (g1.z != 0.0f);
        unsigned long long bal = __ballot(valid);   // r wave-aligned (64 consecutive rows)
        if ((tid & 63) == 0) {
            vwords[(t >> 5) + 0] = (uint32)bal;
            vwords[(t >> 5) + 1] = (uint32)(bal >> 32);
        }
    }
}

// ---------------- NMS stage 2: suppression bitmask build (TRANSPOSED) -----
// rmT[word][row] per batch. Strict upper triangle; diagonal scrubbed here.
// Exact div-free IoU threshold (R5 proof).
#define KMID (13421772.5 / 33554432.0)
__global__ __launch_bounds__(1024) void build_kernel(const float* __restrict__ gx1,
                                                     const float* __restrict__ gy1,
                                                     const float* __restrict__ gx2,
                                                     const float* __restrict__ gy2,
                                                     const float* __restrict__ gar,
                                                     const uint32* __restrict__ gcv,
                                                     uint32* __restrict__ rowmask) {
    __shared__ float  x1s[TOPK], y1s[TOPK], x2s[TOPK], y2s[TOPK];  // 32 KiB
    __shared__ uint32 clss[TOPK];                                  // 8 KiB
    int bt   = blockIdx.y;
    int pr   = blockIdx.x;          // pair 0..15
    int tid  = threadIdx.x;
    int lane = tid & 63;
    int wv   = tid >> 6;            // wave 0..15
    int base = bt * TOPK;
    uint32* rmT = rowmask + (size_t)base * NWORD;   // [word][2048]

    for (int j = tid; j < TOPK; j += 1024) {
        int g = base + j;
        x1s[j] = gx1[g]; y1s[j] = gy1[g]; x2s[j] = gx2[g]; y2s[j] = gy2[g];
        clss[j] = gcv[g] & 0xffu;
    }
    __syncthreads();

    int r  = (wv >> 3) ? (31 - pr) : pr;   // strip index
    int i0 = r * 64 + (wv & 7) * 8;        // this wave's 8 rows

    float rx1[8], ry1[8], rx2[8], ry2[8], rar[8];
    uint32 rcl[8];
#pragma unroll
    for (int k = 0; k < 8; ++k) {
        rx1[k] = x1s[i0 + k]; ry1[k] = y1s[i0 + k];
        rx2[k] = x2s[i0 + k]; ry2[k] = y2s[i0 + k];
        rar[k] = ((rx2[k] - rx1[k]) + 1.0f) * ((ry2[k] - ry1[k]) + 1.0f);
        rcl[k] = clss[i0 + k];
    }

    int j0 = r * 64 + lane;
    float cx1 = x1s[j0], cy1 = y1s[j0], cx2 = x2s[j0], cy2 = y2s[j0];
    uint32 cc = clss[j0];

    for (int cg = r; cg < 32; ++cg) {
        float nx1 = 0.f, ny1 = 0.f, nx2 = 0.f, ny2 = 0.f; uint32 nc = 0;
        if (cg + 1 < 32) {      // prefetch next column group
            int nj = (cg + 1) * 64 + lane;
            nx1 = x1s[nj]; ny1 = y1s[nj]; nx2 = x2s[nj]; ny2 = y2s[nj];
            nc = clss[nj];
        }
        float car = ((cx2 - cx1) + 1.0f) * ((cy2 - cy1) + 1.0f);
        u64 bal[8];
#pragma unroll
        for (int k = 0; k < 8; ++k) {
            float ix1 = fmaxf(rx1[k], cx1);
            float iy1 = fmaxf(ry1[k], cy1);
            float ix2 = fminf(rx2[k], cx2);
            float iy2 = fminf(ry2[k], cy2);
            float iw = fmaxf((ix2 - ix1) + 1.0f, 0.0f);
            float ih = fmaxf((iy2 - iy1) + 1.0f, 0.0f);
            float inter = iw * ih;
            float denom = ((rar[k] + car) - inter) + 1e-16f;
            bool cond = ((double)inter > KMID * (double)denom) && (cc == rcl[k]);
            bal[k] = __ballot(cond);
        }
        // pack: lanes 0..7 -> low words, lanes 8..15 -> high words of rows i0..i0+7
        u64 v = bal[0];
#pragma unroll
        for (int k = 1; k < 8; ++k) if ((lane & 7) == k) v = bal[k];
        uint32 w32 = (lane & 8) ? (uint32)(v >> 32) : (uint32)v;
        int gi = i0 + (lane & 7);
        int wd = 2 * cg + ((lane >> 3) & 1);
        if (wd == (gi >> 5)) w32 &= ~((2u << (gi & 31)) - 1u);   // diagonal scrub
        if (lane < 16) rmT[(size_t)wd * TOPK + gi] = w32;
        cx1 = nx1; cy1 = ny1; cx2 = nx2; cy2 = ny2; cc = nc;
    }
}

// ---------------- NMS scan copy: global_load_lds DMA ----------------
// rmT is [word][row]. For chunk c, word w covers rows c*256..+255 -> ONE
// global_load_lds dwordx4 per word. Trim w >= 8c (dead below).
__device__ __forceinline__ void copy_chunk_dma(const uint32* __restrict__ rmT,
                                               uint32* dstL, int c, int wvm1, int lane) {
    int wmin = 8 * c;
    for (int w = wmin + wvm1; w < 64; w += 15) {
        const uint32* gp = rmT + (size_t)w * TOPK + c * CH + lane * 4;
        uint32* lp = dstL + w * CHP;
        __builtin_amdgcn_global_load_lds((const __attribute__((address_space(1))) void*)gp,
                                         (__attribute__((address_space(3))) void*)lp,
                                         16, 0, 0);
    }
}

// ---------------- NMS stage 3: group-batched greedy scan ----------------
__global__ __launch_bounds__(1024) void scan_kernel(const uint32* __restrict__ rowmask,
                                                    const uint32* __restrict__ vwords,
                                                    float* __restrict__ keepf) {
    __shared__ uint32 buf[2][64 * CHP];   // 2 x 66,560 B
    int bt  = blockIdx.x;
    int tid = threadIdx.x;
    int wv  = tid >> 6;
    int l   = tid & 63;
    const uint32* rmT = rowmask + (size_t)bt * TOPK * NWORD;

    uint32 supp = 0, keepw = 0;
    if (wv == 0) supp = ~vwords[bt * 64 + l];

    if (wv > 0) copy_chunk_dma(rmT, buf[0], 0, wv - 1, l);
    __syncthreads();

    for (int c = 0; c < NCHUNK; ++c) {
        if (wv > 0) {
            if (c + 1 < NCHUNK) copy_chunk_dma(rmT, buf[(c + 1) & 1], c + 1, wv - 1, l);
        } else {
            const uint32* bp = buf[c & 1];
            uint4 sq[8];
            {
                int g0 = c * GPC;
                const uint4* sp = (const uint4*)(bp + g0 * CHP);
#pragma unroll
                for (int q = 0; q < 8; ++q) sq[q] = sp[q];
            }
            for (int gl = 0; gl < GPC; ++gl) {
                int g = c * GPC + gl;
                uint4 rwq[8];
                const uint4* rp = (const uint4*)(bp + l * CHP + gl * 32);
#pragma unroll
                for (int q = 0; q < 8; ++q) rwq[q] = rp[q];
                uint32 cur = __builtin_amdgcn_readlane(supp, g);
#pragma unroll
                for (int q = 0; q < 8; ++q) {
                    uint32 s0 = sq[q].x, s1 = sq[q].y, s2 = sq[q].z, s3 = sq[q].w;
                    int k = q * 4;
                    cur |= s0 & ((((cur >> (k + 0)) & 1u)) - 1u);
                    cur |= s1 & ((((cur >> (k + 1)) & 1u)) - 1u);
                    cur |= s2 & ((((cur >> (k + 2)) & 1u)) - 1u);
                    cur |= s3 & ((((cur >> (k + 3)) & 1u)) - 1u);
                }
                uint32 keep = ~cur;
                if (l == g) keepw = keep;
                if (gl + 1 < GPC) {
                    const uint4* sp = (const uint4*)(bp + (g + 1) * CHP + (gl + 1) * 32);
#pragma unroll
                    for (int q = 0; q < 8; ++q) sq[q] = sp[q];
                }
                uint32 upd = 0;
#pragma unroll
                for (int q = 0; q < 8; ++q) {
                    int k = q * 4;
                    upd |= rwq[q].x & (uint32)(((int)(keep << (31 - (k + 0)))) >> 31);
                    upd |= rwq[q].y & (uint32)(((int)(keep << (31 - (k + 1)))) >> 31);
                    upd |= rwq[q].z & (uint32)(((int)(keep << (31 - (k + 2)))) >> 31);
                    upd |= rwq[q].w & (uint32)(((int)(keep << (31 - (k + 3)))) >> 31);
                }
                supp |= upd;
            }
        }
        __syncthreads();
    }

    if (wv == 0) {
#pragma unroll
        for (int k = 0; k < 32; ++k)
            keepf[bt * TOPK + l * 32 + k] = (float)((keepw >> k) & 1u);
    }
}

extern "C" void kernel_launch(void* const* d_in, const int* in_sizes, int n_in,
                              void* d_out, int out_size, void* d_ws, size_t ws_size,
                              hipStream_t stream) {
    const float* inp     = (const float*)d_in[0];
    const float* anchors = (const float*)d_in[1];
    float* out   = (float*)d_out;                        // [B, N, 25]
    float* topf  = out  + (size_t)B * NCAND * CATTR;     // [B, 2048] indices as float
    float* keepf = topf + (size_t)B * TOPK;              // [B, 2048] 0/1 as float

    // workspace layout
    float*  cws = (float*)d_ws;                          // [B, NCAND] conf
    float*  pk  = cws + B * NCAND;                       // [B, NCAND, 8] packed geom
    float*  gx1 = pk  + (size_t)B * NCAND * 8;
    float*  gy1 = gx1 + B * TOPK;
    float*  gx2 = gy1 + B * TOPK;
    float*  gy2 = gx2 + B * TOPK;
    float*  gar = gy2 + B * TOPK;
    uint32* gcv = (uint32*)(gar + B * TOPK);
    uint32* rowmask = gcv + B * TOPK;                    // rmT: [B][64][2048] u32 = 8 MiB
    uint32* vwords  = rowmask + (size_t)B * TOPK * NWORD;
    // sort scratch aliases onto rowmask (sort+topsel complete before build writes)
    u64* runs = (u64*)rowmask;                           // 1 MiB: [B][4][2048] keys

    decode_kernel<<<(B * NCAND) / 256, 256, 0, stream>>>(inp, anchors, out, cws, pk);
    sort1_kernel<<<B * 4, 256, 0, stream>>>(cws, runs);
    topsel_kernel<<<B, 1024, 0, stream>>>(runs, pk, topf, gx1, gy1, gx2, gy2, gar, gcv, vwords);
    build_kernel<<<dim3(16, B), 1024, 0, stream>>>(gx1, gy1, gx2, gy2, gar, gcv, rowmask);
    scan_kernel<<<B, 1024, 0, stream>>>(rowmask, vwords, keepf);
}